// Round 7
// baseline (1722.632 us; speedup 1.0000x reference)
//
#include <hip/hip_runtime.h>
#include <math.h>

#define BB 128
#define T2 2050
#define TT 2049
#define HH 64
#define GG 448   // 7*H
#define KK 100
#define NE 103   // K+3
#define NSTAGE 2056  // staged ev/dt length (TT + pipeline pad)
#define TCHUNK 128
#define NCHUNK 17    // ceil(2049/128)

#define LOG2E 1.44269504088896340736f
#define LN2   0.69314718055994530942f

// ---- fast transcendentals (native v_exp_f32 / v_log_f32 / v_rcp_f32) ----
__device__ __forceinline__ float frcp(float x) { return __builtin_amdgcn_rcpf(x); }

__device__ __forceinline__ float sigmoid_fast(float x) {
    return frcp(1.f + exp2f(-x * LOG2E));
}
__device__ __forceinline__ float tanh_fast(float x) {
    float e = exp2f(x * (2.f * LOG2E));
    return 1.f - 2.f * frcp(1.f + e);
}
__device__ __forceinline__ float softplus_fast(float x) {
    float t = exp2f(-fabsf(x) * LOG2E);
    return fmaxf(x, 0.f) + LN2 * log2f(1.f + t);
}

// pre_emb[e][t] = sum_k in_emb[e][k] * Wx[k][t] + bias[t]   (103 x 448)
__global__ void pre_emb_kernel(const float* __restrict__ in_emb,
                               const float* __restrict__ Wx,
                               const float* __restrict__ bias,
                               float* __restrict__ pre_emb) {
    int e = blockIdx.x;
    int t = threadIdx.x;
    float acc = bias[t];
#pragma unroll
    for (int k = 0; k < HH; ++k)
        acc = fmaf(in_emb[e * HH + k], Wx[k * GG + t], acc);
    pre_emb[e * GG + t] = acc;
}

// Raw barrier: fence LDS only (lgkmcnt); global loads/stores stay in flight.
__device__ __forceinline__ void step_barrier() {
    __builtin_amdgcn_sched_barrier(0);
    asm volatile("s_waitcnt lgkmcnt(0)" ::: "memory");
    __builtin_amdgcn_s_barrier();
    __builtin_amdgcn_sched_barrier(0);
}

// wave-uniform activation select; gid = gate id (0..6)
__device__ __forceinline__ float act_gate(int gid, float x, float dt) {
    if (gid == 2) return tanh_fast(x);
    if (gid == 6) return exp2f(-dt * log2f(1.f + exp2f(x * LOG2E)));  // exp(-softplus*dt)
    return sigmoid_fast(x);
}

// One block per batch row; 4 waves (one per SIMD), ONE lgkm-only barrier/step.
// The h broadcast is done on the VALU: every wave computes the full state
// redundantly (lane = element, 7 b32 gbuf reads), so lane k's h VGPR holds
// h[k]; v_readlane -> SGPR -> v_fmac(sgpr, w[k]) streams the GEMV with ZERO
// LDS traffic (R6 was LDS-data-return bound at ~12cy per b128 broadcast).
// Wave w owns gates {2w, 2w+1} (wave 3: gate 6 only); lane l owns element l's
// columns; 64 readlane + 128 fmac per step per wave. LDS per step collapses
// to the 7-float gate exchange. Wave 3 streams h_t to out[b,t,0:64]
// (fire-and-forget) for the separate full-GPU logits kernel.
__launch_bounds__(256, 1)
__global__ void scan_kernel(const int* __restrict__ event,
                            const float* __restrict__ dtime,
                            const float* __restrict__ pre_emb,
                            const float* __restrict__ Wh,
                            float* __restrict__ out) {
    const int b   = blockIdx.x;
    const int tid = threadIdx.x;
    const int w   = tid >> 6;     // wave 0..3
    const int l   = tid & 63;     // lane = element

    __shared__ float gbuf[2][7][HH];    // double-buffered gate exchange
    __shared__ int   evoff_s[NSTAGE];   // pre_emb row offsets (float units)
    __shared__ float dtl_s[NSTAGE];

    const int*   ev_row  = event + b * T2;
    const float* dt_row  = dtime + b * T2;
    float*       out_row = out + (size_t)b * TT * KK;

    // ---- stage ev (as row offsets) and dt into LDS (one-time) ----
    for (int i = tid; i < NSTAGE; i += 256) {
        const int idx = (i < T2) ? i : (T2 - 1);
        evoff_s[i] = ev_row[idx] * GG;
        dtl_s[i]   = dt_row[idx];
    }

    // ---- per-lane weight columns (2 per lane, full K) ----
    const int  g0id = 2 * w;
    const int  g1id = 2 * w + 1;
    const bool has2 = (w < 3);                    // wave 3: gate 6 only
    const int  c0   = g0id * 64 + l;
    const int  c1   = has2 ? (g1id * 64 + l) : c0; // clamp: wave3 col1 unused
    float w0[HH], w1[HH];
#pragma unroll
    for (int k = 0; k < HH; ++k) {
        w0[k] = Wh[k * GG + c0];
        w1[k] = Wh[k * GG + c1];
    }

    __syncthreads();   // evoff_s / dtl_s ready

    // ---- prologue: gbuf[0] = act(pre_0) (h_{-1}=0); pre/dt pipelines ----
    {
        const int   o0  = evoff_s[0];
        const float dt0 = dtl_s[1];
        const float p0  = pre_emb[o0 + c0];
        gbuf[0][g0id][l] = act_gate(g0id, p0, dt0);
        if (has2) {
            const float p1 = pre_emb[o0 + c1];
            gbuf[0][g1id][l] = act_gate(g1id, p1, dt0);
        }
    }
    // step t consumes: pre of row ev[t+1] (gates for t+1), dt dtl_s[t+2].
    float preE0 = pre_emb[evoff_s[1] + c0];
    float preE1 = pre_emb[evoff_s[1] + c1];
    float preO0 = pre_emb[evoff_s[2] + c0];
    float preO1 = pre_emb[evoff_s[2] + c1];
    int   offE  = evoff_s[3];
    int   offO  = evoff_s[4];
    float dtE   = dtl_s[2];
    float dtO   = dtl_s[3];

    float c = 0.f, cb = 0.f;
    __syncthreads();

// ---- one scan step (parity-specialized, no register copies) ----
#define STEP(RB, WB, P0, P1, OFF, DTV, TIDX)                                    \
    {                                                                           \
        const float pu0 = P0, pu1 = P1;                                         \
        const float* pb = pre_emb + OFF;                                        \
        P0 = pb[c0];                                                            \
        P1 = pb[c1];                                                            \
        OFF = evoff_s[(TIDX) + 5];                                              \
        const float dtu = DTV;                                                  \
        DTV = dtl_s[(TIDX) + 4];                                                \
        /* state update: lane = element, gates from last step */                \
        const float g0 = gbuf[RB][0][l];                                        \
        const float g1 = gbuf[RB][1][l];                                        \
        const float g2 = gbuf[RB][2][l];                                        \
        const float g3 = gbuf[RB][3][l];                                        \
        const float g4 = gbuf[RB][4][l];                                        \
        const float g5 = gbuf[RB][5][l];                                        \
        const float g6 = gbuf[RB][6][l];   /* = exp(-delta*dt), prefused */     \
        const float ci  = fmaf(g1, c, g0 * g2);                                 \
        const float cbi = fmaf(g5, cb, g4 * g2);                                \
        const float cn  = fmaf(ci - cbi, g6, cbi);                              \
        const float h   = g3 * tanh_fast(cn);                                   \
        c  = cn;                                                                \
        cb = cbi;                                                               \
        if (w == 3) out_row[(size_t)(TIDX) * KK + l] = h;  /* h history */      \
        /* readlane GEMV: h[k] via SGPR, zero LDS traffic */                    \
        const int hb = __builtin_bit_cast(int, h);                              \
        float a00 = 0.f, a01 = 0.f, a02 = 0.f, a03 = 0.f;                       \
        float a10 = 0.f, a11 = 0.f, a12 = 0.f, a13 = 0.f;                       \
        _Pragma("unroll") for (int k = 0; k < HH; k += 4) {                     \
            const float s0 = __builtin_bit_cast(float, __builtin_amdgcn_readlane(hb, k));     \
            const float s1 = __builtin_bit_cast(float, __builtin_amdgcn_readlane(hb, k + 1)); \
            const float s2 = __builtin_bit_cast(float, __builtin_amdgcn_readlane(hb, k + 2)); \
            const float s3 = __builtin_bit_cast(float, __builtin_amdgcn_readlane(hb, k + 3)); \
            a00 = fmaf(s0, w0[k],     a00);                                     \
            a10 = fmaf(s0, w1[k],     a10);                                     \
            a01 = fmaf(s1, w0[k + 1], a01);                                     \
            a11 = fmaf(s1, w1[k + 1], a11);                                     \
            a02 = fmaf(s2, w0[k + 2], a02);                                     \
            a12 = fmaf(s2, w1[k + 2], a12);                                     \
            a03 = fmaf(s3, w0[k + 3], a03);                                     \
            a13 = fmaf(s3, w1[k + 3], a13);                                     \
        }                                                                       \
        const float acc0 = ((a00 + a01) + (a02 + a03)) + pu0;                   \
        gbuf[WB][g0id][l] = act_gate(g0id, acc0, dtu);                          \
        if (has2) {                                                             \
            const float acc1 = ((a10 + a11) + (a12 + a13)) + pu1;               \
            gbuf[WB][g1id][l] = act_gate(g1id, acc1, dtu);                      \
        }                                                                       \
    }

    // main loop: 1024 double-steps cover t = 0..2047
    for (int tp = 0; tp < (TT - 1) / 2; ++tp) {
        const int te = 2 * tp;
        STEP(0, 1, preE0, preE1, offE, dtE, te)
        step_barrier();
        STEP(1, 0, preO0, preO1, offO, dtO, te + 1)
        step_barrier();
    }
    // tail step t = 2048
    STEP(0, 1, preE0, preE1, offE, dtE, TT - 1)

#undef STEP
}

// out[b,t,k] = softplus(dot(h[b,t,:], oe[k,:])), h in out[b,t,0:64].
// No LDS, no barrier: each tt row is loaded (broadcast, L2/L3-resident) and
// stored by ONE wave; the stores data-depend on all loads of that row, so
// the in-place overwrite of h is safe. Wave v handles tt = v, v+4, ...
// Lane owns cols {lane, 64+lane} (second masked to <100).
__launch_bounds__(256)
__global__ void logits_kernel(const float* __restrict__ oe,
                              float* __restrict__ out) {
    const int b    = blockIdx.x;
    const int t0   = blockIdx.y * TCHUNK;
    const int nt   = (TT - t0 < TCHUNK) ? (TT - t0) : TCHUNK;
    const int tid  = threadIdx.x;
    const int wv   = tid >> 6;
    const int lane = tid & 63;

    const int  c1     = (lane < KK - HH) ? (HH + lane) : (KK - 1);
    const bool has_c1 = (lane < KK - HH);

    float wk0[HH], wk1[HH];
#pragma unroll
    for (int qq = 0; qq < HH / 4; ++qq) {
        ((float4*)wk0)[qq] = ((const float4*)(oe + lane * HH))[qq];
        ((float4*)wk1)[qq] = ((const float4*)(oe + c1 * HH))[qq];
    }

    for (int tt = wv; tt < nt; tt += 4) {
        float* row = out + ((size_t)b * TT + t0 + tt) * KK;
        float a0 = 0.f, a1 = 0.f, a2 = 0.f, a3 = 0.f;
        float b0 = 0.f, b1 = 0.f, b2 = 0.f, b3 = 0.f;
#pragma unroll
        for (int qq = 0; qq < HH / 4; ++qq) {
            const float4 hv = ((const float4*)row)[qq];
            a0 = fmaf(hv.x, wk0[4 * qq + 0], a0);
            a1 = fmaf(hv.y, wk0[4 * qq + 1], a1);
            a2 = fmaf(hv.z, wk0[4 * qq + 2], a2);
            a3 = fmaf(hv.w, wk0[4 * qq + 3], a3);
            b0 = fmaf(hv.x, wk1[4 * qq + 0], b0);
            b1 = fmaf(hv.y, wk1[4 * qq + 1], b1);
            b2 = fmaf(hv.z, wk1[4 * qq + 2], b2);
            b3 = fmaf(hv.w, wk1[4 * qq + 3], b3);
        }
        const float lg0 = (a0 + a1) + (a2 + a3);
        const float lg1 = (b0 + b1) + (b2 + b3);
        row[lane] = softplus_fast(lg0);
        if (has_c1) row[HH + lane] = softplus_fast(lg1);
    }
}

extern "C" void kernel_launch(void* const* d_in, const int* in_sizes, int n_in,
                              void* d_out, int out_size, void* d_ws, size_t ws_size,
                              hipStream_t stream) {
    const int*   event  = (const int*)d_in[0];
    const float* dtime  = (const float*)d_in[1];
    const float* in_emb = (const float*)d_in[2];
    const float* Wx     = (const float*)d_in[3];
    const float* Wh     = (const float*)d_in[4];
    const float* bias   = (const float*)d_in[5];
    const float* oe     = (const float*)d_in[6];
    float*       out    = (float*)d_out;

    float* pre_emb = (float*)d_ws;  // 103*448*4 = 184,576 bytes

    pre_emb_kernel<<<NE, GG, 0, stream>>>(in_emb, Wx, bias, pre_emb);
    scan_kernel<<<BB, 256, 0, stream>>>(event, dtime, pre_emb, Wh, out);
    logits_kernel<<<dim3(BB, NCHUNK), 256, 0, stream>>>(oe, out);
}